// Round 4
// baseline (404.776 us; speedup 1.0000x reference)
//
#include <hip/hip_runtime.h>

#define NN 50000
#define EE 800000
#define ET (EE + NN)
#define NCH ((NN + 255) / 256)                       // 196 scan chunks
#define DEGB ((ET + 255) / 256)                      // 3322 degree/fill blocks
#define WPB ((128 * 128 + 128 * 64 + 255) / 256)     // 96 wtprep blocks
#define GEMB ((NN + 63) / 64)                        // 782 gemm blocks
#define NODB ((NN + 3) / 4)                          // 12500 per-node-wave blocks

typedef unsigned short ushort_t;
using bf16x8 = __attribute__((ext_vector_type(8))) short;
using f32x4  = __attribute__((ext_vector_type(4))) float;

__device__ __forceinline__ float bf2f(ushort_t u) {
    return __uint_as_float(((unsigned int)u) << 16);
}
__device__ __forceinline__ ushort_t f2bf(float f) {
    unsigned int u = __float_as_uint(f);
    u += 0x7fffu + ((u >> 16) & 1u);
    return (ushort_t)(u >> 16);
}
__device__ __forceinline__ float lrelu(float e) {
    return fmaxf(e, 0.f) + 0.2f * fminf(e, 0.f);
}
__device__ __forceinline__ float ldf(const void* p, int i, bool f32) {
    return f32 ? ((const float*)p)[i] : bf2f(((const ushort_t*)p)[i]);
}

// ---- block-local dtype sniffers (per-wave ballot) ----
__device__ __forceinline__ bool sniff_f32(const unsigned int* __restrict__ xw) {
    int lane = threadIdx.x & 63;
    float v = __uint_as_float(xw[lane]);
    float a = fabsf(v);
    bool ok = (a > 1e-6f && a < 1e6f) || v == 0.f;
    unsigned long long m = __ballot(ok);
    return __popcll(m) >= 48;
}
__device__ __forceinline__ bool sniff_i64(const int* __restrict__ eiw) {
    int lane = threadIdx.x & 63;
    unsigned long long m = __ballot(eiw[2 * lane + 1] != 0);
    return __popcll(m) <= 4;
}

__device__ __forceinline__ void edge_sd(const int* ei, int i, bool i64, int& s, int& d) {
    if (i < EE) {
        if (i64) { s = ei[2 * i]; d = ei[2 * (EE + i)]; }
        else     { s = ei[i];     d = ei[EE + i]; }
    } else {
        s = d = i - EE;
    }
}
__device__ __forceinline__ int edge_d(const int* ei, int i, bool i64) {
    if (i < EE) return i64 ? ei[2 * (EE + i)] : ei[EE + i];
    return i - EE;
}

// ---------------- L1: degree histogram + rank (atomic-free fill later) + W pre-transpose ----------------
__global__ __launch_bounds__(256) void prep_kernel(const int* __restrict__ ei, int* __restrict__ deg8,
                                                   int* __restrict__ rank,
                                                   const unsigned int* __restrict__ xw,
                                                   const void* W1v, const void* W2v,
                                                   ushort_t* __restrict__ Wt1, ushort_t* __restrict__ Wt2) {
    int b = blockIdx.x;
    if (b < DEGB) {
        bool i64 = sniff_i64(ei);
        int i = b * 256 + threadIdx.x;
        if (i >= ET) return;
        int g = b & 7;                        // blockIdx->XCD round-robin: atomic lines stay in one L2
        int d = edge_d(ei, i, i64);
        rank[i] = atomicAdd(&deg8[(size_t)g * NN + d], 1);
    } else {
        bool f32 = sniff_f32(xw);
        int i = (b - DEGB) * 256 + threadIdx.x;
        if (i < 128 * 128) {                  // W1[k][nc] -> Wt1[nc][k]
            int k = i >> 7, nc = i & 127;
            ushort_t v = f32 ? f2bf(((const float*)W1v)[i]) : ((const ushort_t*)W1v)[i];
            Wt1[nc * 128 + k] = v;
        }
        int j = i - 128 * 128;
        if (j >= 0 && j < 128 * 64) {         // W2[k][nc] -> Wt2[nc][k]
            int k = j >> 6, nc = j & 63;
            ushort_t v = f32 ? f2bf(((const float*)W2v)[j]) : ((const ushort_t*)W2v)[j];
            Wt2[nc * 128 + k] = v;
        }
    }
}

// ---------------- scan: all-publish-then-all-read (no serial lookback chain) ----------------
#define FLG_A (1ull << 62)

__global__ __launch_bounds__(256) void scan_kernel(int* __restrict__ deg8, int* __restrict__ rowptr,
                                                   unsigned long long* __restrict__ state) {
    __shared__ int wsum[4];
    __shared__ int bpref;
    int b = blockIdx.x;
    int t = threadIdx.x;
    int node = b * 256 + t;
    int lane = t & 63, wid = t >> 6;
    int dv[8];
    int v = 0;
    if (node < NN) {
        #pragma unroll
        for (int g = 0; g < 8; ++g) {
            dv[g] = deg8[(size_t)g * NN + node];
            v += dv[g];
        }
    }
    int x = v;
    #pragma unroll
    for (int off = 1; off < 64; off <<= 1) {
        int y = __shfl_up(x, off);
        if (lane >= off) x += y;
    }
    if (lane == 63) wsum[wid] = x;
    __syncthreads();
    if (t < 4) {
        int s = wsum[t];
        #pragma unroll
        for (int off = 1; off < 4; off <<= 1) {
            int y = __shfl_up(s, off);
            if (t >= off) s += y;
        }
        wsum[t] = s;
    }
    __syncthreads();
    int total = wsum[3];                      // block aggregate
    if (t == 0) atomicExch(&state[b], FLG_A | (unsigned long long)(unsigned)total);
    if (t < 64) {                             // wave-parallel prefix: read all predecessors
        int p = 0;
        #pragma unroll
        for (int w = 0; w < (NCH + 63) / 64; ++w) {
            int j = w * 64 + t;
            unsigned long long sv = 0;
            if (j < b) {
                do { sv = atomicAdd(&state[j], 0ull); __builtin_amdgcn_s_sleep(1); } while (!(sv >> 62));
            }
            p += (int)(unsigned)(sv & 0xffffffffull);
        }
        #pragma unroll
        for (int off = 1; off < 64; off <<= 1) p += __shfl_xor(p, off);
        if (t == 0) bpref = p;
    }
    __syncthreads();
    int excl = x - v + ((wid > 0) ? wsum[wid - 1] : 0);
    if (node < NN) {
        int run = bpref + excl;
        rowptr[node] = run;
        #pragma unroll
        for (int g = 0; g < 8; ++g) {         // deg8 becomes per-slice exclusive offsets for fill
            deg8[(size_t)g * NN + node] = run;
            run += dv[g];
        }
    }
    if (b == NCH - 1 && t == 0) rowptr[NN] = bpref + total;
}

// ---------------- MFMA GEMM body; PLANE=true writes h1 in head-plane layout [H][NN][16] ----------------
template <bool AEXT, int NCOL, int NH, bool PLANE>
__device__ __forceinline__ void mgemm_body(int bid, const void* Av, const ushort_t* __restrict__ Wt,
                                           const void* a_src, const void* a_dst,
                                           ushort_t* __restrict__ outb, float* __restrict__ asrc,
                                           float* __restrict__ adst, int n, bool f32) {
    constexpr int K = 128;
    constexpr int NCT = NCOL / 16;
    bool af32 = AEXT && f32;                  // internal A (hmid) is always bf16
    int t = threadIdx.x;
    int lane = t & 63, wid = t >> 6;
    int m = lane & 15, quad = lane >> 4;
    int rbase = bid * 64 + wid * 16;
    int row = rbase + m;
    bool rok = row < n;

    bf16x8 af[4];
    if (rok) {
        if (!af32) {
            const ushort_t* ap = (const ushort_t*)Av + (size_t)row * K + quad * 8;
            #pragma unroll
            for (int kk = 0; kk < 4; ++kk) af[kk] = *(const bf16x8*)(ap + kk * 32);
        } else {
            const float* ap = (const float*)Av + (size_t)row * K + quad * 8;
            #pragma unroll
            for (int kk = 0; kk < 4; ++kk) {
                float4 q0 = *(const float4*)(ap + kk * 32);
                float4 q1 = *(const float4*)(ap + kk * 32 + 4);
                bf16x8 v;
                v[0] = (short)f2bf(q0.x); v[1] = (short)f2bf(q0.y);
                v[2] = (short)f2bf(q0.z); v[3] = (short)f2bf(q0.w);
                v[4] = (short)f2bf(q1.x); v[5] = (short)f2bf(q1.y);
                v[6] = (short)f2bf(q1.z); v[7] = (short)f2bf(q1.w);
                af[kk] = v;
            }
        }
    } else {
        #pragma unroll
        for (int kk = 0; kk < 4; ++kk) af[kk] = (bf16x8){0, 0, 0, 0, 0, 0, 0, 0};
    }

    f32x4 acc[NCT];
    #pragma unroll
    for (int c = 0; c < NCT; ++c) acc[c] = (f32x4){0.f, 0.f, 0.f, 0.f};

    const ushort_t* wp = Wt + (size_t)m * K + quad * 8;
    #pragma unroll
    for (int c = 0; c < NCT; ++c) {
        const ushort_t* wc = wp + (size_t)c * 16 * K;
        #pragma unroll
        for (int kk = 0; kk < 4; ++kk) {
            bf16x8 bf = *(const bf16x8*)(wc + kk * 32);
            acc[c] = __builtin_amdgcn_mfma_f32_16x16x32_bf16(af[kk], bf, acc[c], 0, 0, 0);
        }
    }

    int orow0 = rbase + quad * 4;
    #pragma unroll
    for (int c = 0; c < NCT; ++c) {
        #pragma unroll
        for (int r = 0; r < 4; ++r) {
            int orow = orow0 + r;
            if (orow < n) {
                if (PLANE) outb[((size_t)c * n + orow) * 16 + m] = f2bf(acc[c][r]);
                else       outb[(size_t)orow * NCOL + c * 16 + m] = f2bf(acc[c][r]);
            }
        }
    }

    if (NH == 8) {
        #pragma unroll
        for (int c = 0; c < NCT; ++c) {
            float as = ldf(a_src, c * 16 + m, f32);
            float ad = ldf(a_dst, c * 16 + m, f32);
            float ps[4], pd[4];
            #pragma unroll
            for (int r = 0; r < 4; ++r) { ps[r] = acc[c][r] * as; pd[r] = acc[c][r] * ad; }
            #pragma unroll
            for (int stp = 1; stp < 16; stp <<= 1) {
                #pragma unroll
                for (int r = 0; r < 4; ++r) {
                    ps[r] += __shfl_xor(ps[r], stp);
                    pd[r] += __shfl_xor(pd[r], stp);
                }
            }
            if (m == 0) {
                #pragma unroll
                for (int r = 0; r < 4; ++r) {
                    int orow = orow0 + r;
                    if (orow < n) {
                        asrc[(size_t)orow * 8 + c] = ps[r];
                        adst[(size_t)orow * 8 + c] = pd[r];
                    }
                }
            }
        }
    } else {
        float ps[4] = {0.f, 0.f, 0.f, 0.f}, pd[4] = {0.f, 0.f, 0.f, 0.f};
        #pragma unroll
        for (int c = 0; c < NCT; ++c) {
            float as = ldf(a_src, c * 16 + m, f32);
            float ad = ldf(a_dst, c * 16 + m, f32);
            #pragma unroll
            for (int r = 0; r < 4; ++r) {
                ps[r] = fmaf(acc[c][r], as, ps[r]);
                pd[r] = fmaf(acc[c][r], ad, pd[r]);
            }
        }
        #pragma unroll
        for (int stp = 1; stp < 16; stp <<= 1) {
            #pragma unroll
            for (int r = 0; r < 4; ++r) {
                ps[r] += __shfl_xor(ps[r], stp);
                pd[r] += __shfl_xor(pd[r], stp);
            }
        }
        if (m == 0) {
            #pragma unroll
            for (int r = 0; r < 4; ++r) {
                int orow = orow0 + r;
                if (orow < n) { asrc[orow] = ps[r]; adst[orow] = pd[r]; }
            }
        }
    }
}

// ---------------- L3: layer-1 GEMM (plane output) + CSR fill, fused by block range ----------------
__global__ __launch_bounds__(256) void gemm1_fill_kernel(const void* xv, const ushort_t* __restrict__ Wt1,
                                                         const void* as1, const void* ad1,
                                                         ushort_t* __restrict__ h1p,
                                                         float* __restrict__ asrc1, float* __restrict__ adst1,
                                                         const int* __restrict__ ei,
                                                         const int* __restrict__ deg8off,
                                                         const int* __restrict__ rank, int* __restrict__ col) {
    if (blockIdx.x < GEMB) {
        bool f32 = sniff_f32((const unsigned int*)xv);
        mgemm_body<true, 128, 8, true>(blockIdx.x, xv, Wt1, as1, ad1, h1p, asrc1, adst1, NN, f32);
        return;
    }
    int bb = blockIdx.x - GEMB;               // fill range: same geometry as prep's degree range
    bool i64 = sniff_i64(ei);
    int i = bb * 256 + threadIdx.x;
    if (i >= ET) return;
    int g = bb & 7;                           // same blockIdx->g map as the degree pass
    int s, d;
    edge_sd(ei, i, i64, s, d);
    col[deg8off[(size_t)g * NN + d] + rank[i]] = s;
}

__global__ __launch_bounds__(256) void mgemm2_kernel(const void* Av, const ushort_t* __restrict__ Wt,
                                                     const void* a_src, const void* a_dst,
                                                     ushort_t* __restrict__ outb, float* __restrict__ asrc,
                                                     float* __restrict__ adst, const unsigned int* __restrict__ xw) {
    bool f32 = sniff_f32(xw);
    mgemm_body<false, 64, 1, false>(blockIdx.x, Av, Wt, a_src, a_dst, outb, asrc, adst, NN, f32);
}

// ---------------- alpha1: per dst node, normalized attention weights -> 8 head planes [8][ET] bf16 ----------------
// asrc1 table is 1.6MB (L2-resident) so the random 32B gathers hit L2. One wave per node.
__global__ __launch_bounds__(256) void alpha1_kernel(const int* __restrict__ rowptr, const int* __restrict__ col,
                                                     const float* __restrict__ asrc, const float* __restrict__ adst,
                                                     ushort_t* __restrict__ aplane) {
    int lane = threadIdx.x & 63, wid = threadIdx.x >> 6;
    int d = blockIdx.x * 4 + wid;
    if (d >= NN) return;
    int start = rowptr[d], end = rowptr[d + 1];
    const float4* dp = (const float4*)(adst + (size_t)d * 8);
    float4 ad0 = dp[0], ad1 = dp[1];
    float ss[8] = {0.f, 0.f, 0.f, 0.f, 0.f, 0.f, 0.f, 0.f};
    float ex0[8];
    for (int chunk = start; chunk < end; chunk += 64) {
        int idx = chunk + lane;
        float e[8];
        if (idx < end) {
            int c = col[idx];
            const float4* ap = (const float4*)(asrc + (size_t)c * 8);
            float4 s0 = ap[0], s1 = ap[1];
            e[0] = __expf(lrelu(s0.x + ad0.x));
            e[1] = __expf(lrelu(s0.y + ad0.y));
            e[2] = __expf(lrelu(s0.z + ad0.z));
            e[3] = __expf(lrelu(s0.w + ad0.w));
            e[4] = __expf(lrelu(s1.x + ad1.x));
            e[5] = __expf(lrelu(s1.y + ad1.y));
            e[6] = __expf(lrelu(s1.z + ad1.z));
            e[7] = __expf(lrelu(s1.w + ad1.w));
        } else {
            #pragma unroll
            for (int k = 0; k < 8; ++k) e[k] = 0.f;
        }
        #pragma unroll
        for (int k = 0; k < 8; ++k) ss[k] += e[k];
        if (chunk == start) {
            #pragma unroll
            for (int k = 0; k < 8; ++k) ex0[k] = e[k];
        }
    }
    #pragma unroll
    for (int off = 1; off < 64; off <<= 1) {
        #pragma unroll
        for (int k = 0; k < 8; ++k) ss[k] += __shfl_xor(ss[k], off);
    }
    float inv[8];
    #pragma unroll
    for (int k = 0; k < 8; ++k) inv[k] = 1.f / (ss[k] + 1e-16f);
    // store pass: first chunk from register cache; rare extra chunks recomputed
    {
        int idx = start + lane;
        if (idx < end) {
            #pragma unroll
            for (int k = 0; k < 8; ++k)
                aplane[(size_t)k * ET + idx] = f2bf(ex0[k] * inv[k]);
        }
    }
    for (int chunk = start + 64; chunk < end; chunk += 64) {
        int idx = chunk + lane;
        if (idx < end) {
            int c = col[idx];
            const float4* ap = (const float4*)(asrc + (size_t)c * 8);
            float4 s0 = ap[0], s1 = ap[1];
            float e[8];
            e[0] = __expf(lrelu(s0.x + ad0.x));
            e[1] = __expf(lrelu(s0.y + ad0.y));
            e[2] = __expf(lrelu(s0.z + ad0.z));
            e[3] = __expf(lrelu(s0.w + ad0.w));
            e[4] = __expf(lrelu(s1.x + ad1.x));
            e[5] = __expf(lrelu(s1.y + ad1.y));
            e[6] = __expf(lrelu(s1.z + ad1.z));
            e[7] = __expf(lrelu(s1.w + ad1.w));
            #pragma unroll
            for (int k = 0; k < 8; ++k)
                aplane[(size_t)k * ET + idx] = f2bf(e[k] * inv[k]);
        }
    }
}

// ---------------- agg1b: head-sharded weighted gather; group = blockIdx&7 tracks XCD round-robin ----------------
// XCD h's L2 holds plane h (1.6MB) + alpha plane h (1.7MB) -> gathers become L2 hits.
// col/alpha are streamed once per group: nontemporal to protect the hot plane.
// Wave layout: 16 edges in flight x 4 lanes/edge (uint2 = 4 dims each).
__global__ __launch_bounds__(256) void agg1b_kernel(const unsigned int* __restrict__ xw,
                                                    const int* __restrict__ rowptr, const int* __restrict__ col,
                                                    const ushort_t* __restrict__ h1p,
                                                    const ushort_t* __restrict__ aplane,
                                                    const void* b1, ushort_t* __restrict__ hmidb) {
    __shared__ float wal[4][64];
    __shared__ int loff[4][64];
    bool f32 = sniff_f32(xw);
    int lane = threadIdx.x & 63, wid = threadIdx.x >> 6;
    int h = blockIdx.x & 7;
    int d = (blockIdx.x >> 3) * 4 + wid;
    if (d >= NN) return;                 // per-wave LDS slices; no __syncthreads
    int start = rowptr[d], end = rowptr[d + 1];
    int el = lane >> 2, dl = lane & 3;   // edge slot 0..15, dim quarter 0..3
    const char* pb = (const char*)(h1p + (size_t)h * NN * 16) + dl * 8;
    const ushort_t* ap = aplane + (size_t)h * ET;
    float a0 = 0.f, a1 = 0.f, a2 = 0.f, a3 = 0.f;
    for (int chunk = start; chunk < end; chunk += 64) {
        int idx = chunk + lane;
        int cnt = min(64, end - chunk);
        int c = (idx < end) ? __builtin_nontemporal_load(&col[idx]) : 0;
        loff[wid][lane] = c << 5;        // byte offset of 32B plane row (0 for tail: safe)
        float av = 0.f;
        if (lane < cnt) av = bf2f(__builtin_nontemporal_load(&ap[idx]));
        wal[wid][lane] = av;             // tail alpha = 0 -> contributes nothing
        int niter = (cnt + 15) >> 4;
        #pragma unroll 4
        for (int jj = 0; jj < niter; ++jj) {
            int j = jj * 16 + el;
            int off = loff[wid][j];
            float a = wal[wid][j];
            uint2 hv = *(const uint2*)(pb + off);
            a0 = fmaf(a, __uint_as_float(hv.x << 16), a0);
            a1 = fmaf(a, __uint_as_float(hv.x & 0xffff0000u), a1);
            a2 = fmaf(a, __uint_as_float(hv.y << 16), a2);
            a3 = fmaf(a, __uint_as_float(hv.y & 0xffff0000u), a3);
        }
    }
    #pragma unroll
    for (int off = 4; off < 64; off <<= 1) {
        a0 += __shfl_xor(a0, off);
        a1 += __shfl_xor(a1, off);
        a2 += __shfl_xor(a2, off);
        a3 += __shfl_xor(a3, off);
    }
    if (el == 0) {                        // lanes 0..3 write dims [h*16+dl*4, +4)
        int db = h * 16 + dl * 4;
        float o0 = a0 + ldf(b1, db + 0, f32);
        float o1 = a1 + ldf(b1, db + 1, f32);
        float o2 = a2 + ldf(b1, db + 2, f32);
        float o3 = a3 + ldf(b1, db + 3, f32);
        o0 = (o0 > 0.f) ? o0 : (__expf(o0) - 1.f);   // ELU
        o1 = (o1 > 0.f) ? o1 : (__expf(o1) - 1.f);
        o2 = (o2 > 0.f) ? o2 : (__expf(o2) - 1.f);
        o3 = (o3 > 0.f) ? o3 : (__expf(o3) - 1.f);
        uint2 pk;
        pk.x = ((unsigned int)f2bf(o1) << 16) | (unsigned int)f2bf(o0);
        pk.y = ((unsigned int)f2bf(o3) << 16) | (unsigned int)f2bf(o2);
        *(uint2*)(hmidb + (size_t)d * 128 + db) = pk;
    }
}

// ---------------- layer-2 aggregation: wide-gather (8 edges x 1KB per VMEM instr) + log_softmax ----------------
__global__ __launch_bounds__(256) void agg2_kernel(const unsigned int* __restrict__ xw,
                                                   const int* __restrict__ rowptr, const int* __restrict__ col,
                                                   const ushort_t* __restrict__ h2b,
                                                   const float* __restrict__ asrc, const float* __restrict__ adst,
                                                   const void* b2, float* __restrict__ out) {
    __shared__ float wle[4][64];
    __shared__ int loff[4][64];
    bool f32 = sniff_f32(xw);
    int lane = threadIdx.x & 63, wid = threadIdx.x >> 6;
    int d = blockIdx.x * 4 + wid;
    if (d >= NN) return;
    int start = rowptr[d], end = rowptr[d + 1];
    int sub = lane & 7;                  // dim group: classes [8*sub, 8*sub+8)
    int eg  = lane >> 3;                 // edge group 0..7
    float ad = adst[d];
    const char* hb = (const char*)h2b + sub * 16;
    float acc[8] = {0.f, 0.f, 0.f, 0.f, 0.f, 0.f, 0.f, 0.f};
    float ssum = 0.f;
    for (int chunk = start; chunk < end; chunk += 64) {
        int cnt = min(64, end - chunk);
        int c = (chunk + lane < end) ? col[chunk + lane] : 0;
        loff[wid][lane] = c << 7;        // byte offset of 128B h2b row (0 for tail: safe)
        float e = 0.f;
        if (lane < cnt) e = __expf(lrelu(asrc[c] + ad));
        wle[wid][lane] = e;
        int niter = (cnt + 7) >> 3;
        #pragma unroll 2
        for (int jj = 0; jj < niter; ++jj) {
            int j = jj * 8 + eg;
            int off = loff[wid][j];
            float ex = wle[wid][j];
            uint4 hv = *(const uint4*)(hb + off);
            ssum += ex;
            acc[0] = fmaf(ex, __uint_as_float(hv.x << 16), acc[0]);
            acc[1] = fmaf(ex, __uint_as_float(hv.x & 0xffff0000u), acc[1]);
            acc[2] = fmaf(ex, __uint_as_float(hv.y << 16), acc[2]);
            acc[3] = fmaf(ex, __uint_as_float(hv.y & 0xffff0000u), acc[3]);
            acc[4] = fmaf(ex, __uint_as_float(hv.z << 16), acc[4]);
            acc[5] = fmaf(ex, __uint_as_float(hv.z & 0xffff0000u), acc[5]);
            acc[6] = fmaf(ex, __uint_as_float(hv.w << 16), acc[6]);
            acc[7] = fmaf(ex, __uint_as_float(hv.w & 0xffff0000u), acc[7]);
        }
    }
    #pragma unroll
    for (int off = 8; off < 64; off <<= 1) {
        ssum += __shfl_xor(ssum, off);
        #pragma unroll
        for (int k = 0; k < 8; ++k) acc[k] += __shfl_xor(acc[k], off);
    }
    if (eg == 0) {                        // lanes 0..7 hold the full 64-class row, 8 classes each
        float inv = 1.f / (ssum + 1e-16f);
        float o[8];
        #pragma unroll
        for (int k = 0; k < 8; ++k) o[k] = fmaf(acc[k], inv, ldf(b2, sub * 8 + k, f32));
        float mm = o[0];
        #pragma unroll
        for (int k = 1; k < 8; ++k) mm = fmaxf(mm, o[k]);
        #pragma unroll
        for (int off = 1; off < 8; off <<= 1) mm = fmaxf(mm, __shfl_xor(mm, off));
        float ts = 0.f;
        #pragma unroll
        for (int k = 0; k < 8; ++k) ts += __expf(o[k] - mm);
        #pragma unroll
        for (int off = 1; off < 8; off <<= 1) ts += __shfl_xor(ts, off);
        float lg = mm + __logf(ts);
        float4 w0, w1, l0, l1;
        w0.x = o[0]; w0.y = o[1]; w0.z = o[2]; w0.w = o[3];
        w1.x = o[4]; w1.y = o[5]; w1.z = o[6]; w1.w = o[7];
        l0.x = o[0] - lg; l0.y = o[1] - lg; l0.z = o[2] - lg; l0.w = o[3] - lg;
        l1.x = o[4] - lg; l1.y = o[5] - lg; l1.z = o[6] - lg; l1.w = o[7] - lg;
        float* op = out + (size_t)d * 64 + sub * 8;
        *(float4*)op = w0;
        *(float4*)(op + 4) = w1;
        float* lp = out + (size_t)NN * 64 + (size_t)d * 64 + sub * 8;
        *(float4*)lp = l0;
        *(float4*)(lp + 4) = l1;
    }
}

extern "C" void kernel_launch(void* const* d_in, const int* in_sizes, int n_in,
                              void* d_out, int out_size, void* d_ws, size_t ws_size,
                              hipStream_t stream) {
    const void* x   = d_in[0];
    const int*  ei  = (const int*)d_in[1];
    const void* W1  = d_in[2];
    const void* as1 = d_in[3];
    const void* ad1 = d_in[4];
    const void* b1  = d_in[5];
    const void* W2  = d_in[6];
    const void* as2 = d_in[7];
    const void* ad2 = d_in[8];
    const void* b2  = d_in[9];
    float* out = (float*)d_out;

    char* w = (char*)d_ws;
    auto alloc = [&](size_t bytes) {
        void* p = (void*)w;
        w += (bytes + 255) & ~(size_t)255;
        return p;
    };
    int* deg8     = (int*)alloc((size_t)8 * NN * 4 + 4096);   // +state tail (zeroed together)
    unsigned long long* state = (unsigned long long*)((char*)deg8 + (size_t)8 * NN * 4);
    int* rowptr   = (int*)alloc((size_t)(NN + 1) * 4);
    int* rank     = (int*)alloc((size_t)ET * 4);
    int* colx     = (int*)alloc((size_t)ET * 4);
    ushort_t* Wt1 = (ushort_t*)alloc((size_t)128 * 128 * 2);
    ushort_t* Wt2 = (ushort_t*)alloc((size_t)64 * 128 * 2);
    ushort_t* h1p = (ushort_t*)alloc((size_t)8 * NN * 16 * 2);   // head planes [8][NN][16]
    float* asrc1  = (float*)alloc((size_t)NN * 8 * 4);
    float* adst1  = (float*)alloc((size_t)NN * 8 * 4);
    ushort_t* aplane = (ushort_t*)alloc((size_t)8 * ET * 2);     // alpha planes [8][ET]
    ushort_t* hmidb = (ushort_t*)alloc((size_t)NN * 128 * 2);
    ushort_t* h2b = (ushort_t*)alloc((size_t)NN * 64 * 2);
    float* asrc2  = (float*)alloc((size_t)NN * 4);
    float* adst2  = (float*)alloc((size_t)NN * 4);

    hipMemsetAsync(deg8, 0, (size_t)8 * NN * 4 + (size_t)NCH * 8, stream);

    prep_kernel<<<DEGB + WPB, 256, 0, stream>>>(ei, deg8, rank, (const unsigned int*)x, W1, W2, Wt1, Wt2);
    scan_kernel<<<NCH, 256, 0, stream>>>(deg8, rowptr, state);
    gemm1_fill_kernel<<<GEMB + DEGB, 256, 0, stream>>>(x, Wt1, as1, ad1, h1p, asrc1, adst1,
                                                       ei, deg8, rank, colx);
    alpha1_kernel<<<NODB, 256, 0, stream>>>(rowptr, colx, asrc1, adst1, aplane);
    agg1b_kernel<<<NODB * 8, 256, 0, stream>>>((const unsigned int*)x, rowptr, colx, h1p,
                                               aplane, b1, hmidb);
    mgemm2_kernel<<<GEMB, 256, 0, stream>>>((const void*)hmidb, Wt2, as2, ad2, h2b, asrc2, adst2,
                                            (const unsigned int*)x);
    agg2_kernel<<<NODB, 256, 0, stream>>>((const unsigned int*)x, rowptr, colx, h2b,
                                          asrc2, adst2, b2, out);
}

// Round 5
// 373.879 us; speedup vs baseline: 1.0826x; 1.0826x over previous
//
#include <hip/hip_runtime.h>

#define NN 50000
#define EE 800000
#define ET (EE + NN)
#define NCH ((NN + 255) / 256)                       // 196 scan chunks
#define DEG4B ((ET + 1023) / 1024)                   // 831 degree/fill blocks (4 edges/thread)
#define WPB ((128 * 128 + 128 * 64 + 255) / 256)     // 96 wtprep blocks
#define GEMB ((NN + 63) / 64)                        // 782 gemm blocks
#define NODB ((NN + 3) / 4)                          // 12500 per-node-wave blocks

typedef unsigned short ushort_t;
using bf16x8 = __attribute__((ext_vector_type(8))) short;
using f32x4  = __attribute__((ext_vector_type(4))) float;

__device__ __forceinline__ float bf2f(ushort_t u) {
    return __uint_as_float(((unsigned int)u) << 16);
}
__device__ __forceinline__ ushort_t f2bf(float f) {
    unsigned int u = __float_as_uint(f);
    u += 0x7fffu + ((u >> 16) & 1u);
    return (ushort_t)(u >> 16);
}
__device__ __forceinline__ float lrelu(float e) {
    return fmaxf(e, 0.f) + 0.2f * fminf(e, 0.f);
}
__device__ __forceinline__ float ldf(const void* p, int i, bool f32) {
    return f32 ? ((const float*)p)[i] : bf2f(((const ushort_t*)p)[i]);
}

// ---- block-local dtype sniffers (per-wave ballot) ----
__device__ __forceinline__ bool sniff_f32(const unsigned int* __restrict__ xw) {
    int lane = threadIdx.x & 63;
    float v = __uint_as_float(xw[lane]);
    float a = fabsf(v);
    bool ok = (a > 1e-6f && a < 1e6f) || v == 0.f;
    unsigned long long m = __ballot(ok);
    return __popcll(m) >= 48;
}
__device__ __forceinline__ bool sniff_i64(const int* __restrict__ eiw) {
    int lane = threadIdx.x & 63;
    unsigned long long m = __ballot(eiw[2 * lane + 1] != 0);
    return __popcll(m) <= 4;
}

// 4-edge batched src/dst fetch. Thread's 4 edges never straddle the EE boundary
// (EE % 4 == 0 and i0 % 4 == 0), so the vector paths are safe.
__device__ __forceinline__ void edge_d4(const int* __restrict__ ei, int i0, bool i64, int (&d)[4]) {
    if (i0 < EE) {
        if (i64) {
            int4 r = *(const int4*)(ei + 2 * (size_t)(EE + i0));
            int4 u = *(const int4*)(ei + 2 * (size_t)(EE + i0) + 4);
            d[0] = r.x; d[1] = r.z; d[2] = u.x; d[3] = u.z;
        } else {
            int4 dv = *(const int4*)(ei + (size_t)EE + i0);
            d[0] = dv.x; d[1] = dv.y; d[2] = dv.z; d[3] = dv.w;
        }
    } else {
        #pragma unroll
        for (int e = 0; e < 4; ++e) d[e] = i0 + e - EE;   // self-loops (guard on use)
    }
}
__device__ __forceinline__ void edge_s4(const int* __restrict__ ei, int i0, bool i64, int (&s)[4]) {
    if (i0 < EE) {
        if (i64) {
            int4 p = *(const int4*)(ei + 2 * (size_t)i0);
            int4 q = *(const int4*)(ei + 2 * (size_t)i0 + 4);
            s[0] = p.x; s[1] = p.z; s[2] = q.x; s[3] = q.z;
        } else {
            int4 sv = *(const int4*)(ei + (size_t)i0);
            s[0] = sv.x; s[1] = sv.y; s[2] = sv.z; s[3] = sv.w;
        }
    } else {
        #pragma unroll
        for (int e = 0; e < 4; ++e) s[e] = i0 + e - EE;
    }
}

// ---------------- L1: degree+rank (4 edges/thread -> 4 atomics in flight) + W pre-transpose ----------------
__global__ __launch_bounds__(256) void prep_kernel(const int* __restrict__ ei, int* __restrict__ deg8,
                                                   int* __restrict__ rank,
                                                   const unsigned int* __restrict__ xw,
                                                   const void* W1v, const void* W2v,
                                                   ushort_t* __restrict__ Wt1, ushort_t* __restrict__ Wt2) {
    int b = blockIdx.x;
    if (b < DEG4B) {
        bool i64 = sniff_i64(ei);
        int i0 = (b * 256 + threadIdx.x) * 4;
        if (i0 >= ET) return;
        int g = b & 7;                        // blockIdx->XCD round-robin: atomic lines stay in one L2
        int d[4], r[4];
        edge_d4(ei, i0, i64, d);
        #pragma unroll
        for (int e = 0; e < 4; ++e)
            if (i0 + e < ET) r[e] = atomicAdd(&deg8[(size_t)g * NN + d[e]], 1);
        if (i0 + 3 < ET) {
            int4 rv; rv.x = r[0]; rv.y = r[1]; rv.z = r[2]; rv.w = r[3];
            *(int4*)(rank + i0) = rv;
        } else {
            #pragma unroll
            for (int e = 0; e < 4; ++e) if (i0 + e < ET) rank[i0 + e] = r[e];
        }
    } else {
        bool f32 = sniff_f32(xw);
        int i = (b - DEG4B) * 256 + threadIdx.x;
        if (i < 128 * 128) {                  // W1[k][nc] -> Wt1[nc][k]
            int k = i >> 7, nc = i & 127;
            ushort_t v = f32 ? f2bf(((const float*)W1v)[i]) : ((const ushort_t*)W1v)[i];
            Wt1[nc * 128 + k] = v;
        }
        int j = i - 128 * 128;
        if (j >= 0 && j < 128 * 64) {         // W2[k][nc] -> Wt2[nc][k]
            int k = j >> 6, nc = j & 63;
            ushort_t v = f32 ? f2bf(((const float*)W2v)[j]) : ((const ushort_t*)W2v)[j];
            Wt2[nc * 128 + k] = v;
        }
    }
}

// ---------------- scan: all-publish-then-all-read (no serial lookback chain) ----------------
#define FLG_A (1ull << 62)

__global__ __launch_bounds__(256) void scan_kernel(int* __restrict__ deg8, int* __restrict__ rowptr,
                                                   unsigned long long* __restrict__ state) {
    __shared__ int wsum[4];
    __shared__ int bpref;
    int b = blockIdx.x;
    int t = threadIdx.x;
    int node = b * 256 + t;
    int lane = t & 63, wid = t >> 6;
    int dv[8];
    int v = 0;
    if (node < NN) {
        #pragma unroll
        for (int g = 0; g < 8; ++g) {
            dv[g] = deg8[(size_t)g * NN + node];
            v += dv[g];
        }
    }
    int x = v;
    #pragma unroll
    for (int off = 1; off < 64; off <<= 1) {
        int y = __shfl_up(x, off);
        if (lane >= off) x += y;
    }
    if (lane == 63) wsum[wid] = x;
    __syncthreads();
    if (t < 4) {
        int s = wsum[t];
        #pragma unroll
        for (int off = 1; off < 4; off <<= 1) {
            int y = __shfl_up(s, off);
            if (t >= off) s += y;
        }
        wsum[t] = s;
    }
    __syncthreads();
    int total = wsum[3];                      // block aggregate
    if (t == 0) atomicExch(&state[b], FLG_A | (unsigned long long)(unsigned)total);
    if (t < 64) {                             // wave-parallel prefix: read all predecessors
        int p = 0;
        #pragma unroll
        for (int w = 0; w < (NCH + 63) / 64; ++w) {
            int j = w * 64 + t;
            unsigned long long sv = 0;
            if (j < b) {
                do { sv = atomicAdd(&state[j], 0ull); __builtin_amdgcn_s_sleep(1); } while (!(sv >> 62));
            }
            p += (int)(unsigned)(sv & 0xffffffffull);
        }
        #pragma unroll
        for (int off = 1; off < 64; off <<= 1) p += __shfl_xor(p, off);
        if (t == 0) bpref = p;
    }
    __syncthreads();
    int excl = x - v + ((wid > 0) ? wsum[wid - 1] : 0);
    if (node < NN) {
        int run = bpref + excl;
        rowptr[node] = run;
        #pragma unroll
        for (int g = 0; g < 8; ++g) {         // deg8 becomes per-slice exclusive offsets for fill
            deg8[(size_t)g * NN + node] = run;
            run += dv[g];
        }
    }
    if (b == NCH - 1 && t == 0) rowptr[NN] = bpref + total;
}

// ---------------- layer-1 MFMA GEMM body (A streamed global->VGPR, B (Wt1) L2-resident) ----------------
__device__ __forceinline__ void mgemm1_body(int bid, const void* Av, const ushort_t* __restrict__ Wt,
                                            const void* a_src, const void* a_dst,
                                            ushort_t* __restrict__ outb, float* __restrict__ asrc,
                                            float* __restrict__ adst, bool f32) {
    constexpr int K = 128;
    constexpr int NCT = 8;
    int t = threadIdx.x;
    int lane = t & 63, wid = t >> 6;
    int m = lane & 15, quad = lane >> 4;
    int rbase = bid * 64 + wid * 16;
    int row = rbase + m;
    bool rok = row < NN;

    bf16x8 af[4];
    if (rok) {
        if (!f32) {
            const ushort_t* ap = (const ushort_t*)Av + (size_t)row * K + quad * 8;
            #pragma unroll
            for (int kk = 0; kk < 4; ++kk) af[kk] = *(const bf16x8*)(ap + kk * 32);
        } else {
            const float* ap = (const float*)Av + (size_t)row * K + quad * 8;
            #pragma unroll
            for (int kk = 0; kk < 4; ++kk) {
                float4 q0 = *(const float4*)(ap + kk * 32);
                float4 q1 = *(const float4*)(ap + kk * 32 + 4);
                bf16x8 v;
                v[0] = (short)f2bf(q0.x); v[1] = (short)f2bf(q0.y);
                v[2] = (short)f2bf(q0.z); v[3] = (short)f2bf(q0.w);
                v[4] = (short)f2bf(q1.x); v[5] = (short)f2bf(q1.y);
                v[6] = (short)f2bf(q1.z); v[7] = (short)f2bf(q1.w);
                af[kk] = v;
            }
        }
    } else {
        #pragma unroll
        for (int kk = 0; kk < 4; ++kk) af[kk] = (bf16x8){0, 0, 0, 0, 0, 0, 0, 0};
    }

    f32x4 acc[NCT];
    #pragma unroll
    for (int c = 0; c < NCT; ++c) acc[c] = (f32x4){0.f, 0.f, 0.f, 0.f};

    const ushort_t* wp = Wt + (size_t)m * K + quad * 8;
    #pragma unroll
    for (int c = 0; c < NCT; ++c) {
        const ushort_t* wc = wp + (size_t)c * 16 * K;
        #pragma unroll
        for (int kk = 0; kk < 4; ++kk) {
            bf16x8 bf = *(const bf16x8*)(wc + kk * 32);
            acc[c] = __builtin_amdgcn_mfma_f32_16x16x32_bf16(af[kk], bf, acc[c], 0, 0, 0);
        }
    }

    int orow0 = rbase + quad * 4;
    #pragma unroll
    for (int c = 0; c < NCT; ++c) {
        #pragma unroll
        for (int r = 0; r < 4; ++r) {
            int orow = orow0 + r;
            if (orow < NN) outb[(size_t)orow * 128 + c * 16 + m] = f2bf(acc[c][r]);
        }
    }

    #pragma unroll
    for (int c = 0; c < NCT; ++c) {           // c == head
        float as = ldf(a_src, c * 16 + m, f32);
        float ad = ldf(a_dst, c * 16 + m, f32);
        float ps[4], pd[4];
        #pragma unroll
        for (int r = 0; r < 4; ++r) { ps[r] = acc[c][r] * as; pd[r] = acc[c][r] * ad; }
        #pragma unroll
        for (int stp = 1; stp < 16; stp <<= 1) {
            #pragma unroll
            for (int r = 0; r < 4; ++r) {
                ps[r] += __shfl_xor(ps[r], stp);
                pd[r] += __shfl_xor(pd[r], stp);
            }
        }
        if (m == 0) {
            #pragma unroll
            for (int r = 0; r < 4; ++r) {
                int orow = orow0 + r;
                if (orow < NN) {
                    asrc[(size_t)orow * 8 + c] = ps[r];
                    adst[(size_t)orow * 8 + c] = pd[r];
                }
            }
        }
    }
}

// ---------------- L3: layer-1 GEMM + CSR fill (4 edges/thread), fused by block range ----------------
__global__ __launch_bounds__(256) void gemm1_fill_kernel(const void* xv, const ushort_t* __restrict__ Wt1,
                                                         const void* as1, const void* ad1,
                                                         ushort_t* __restrict__ h1b,
                                                         float* __restrict__ asrc1, float* __restrict__ adst1,
                                                         const int* __restrict__ ei,
                                                         const int* __restrict__ deg8off,
                                                         const int* __restrict__ rank, int* __restrict__ col) {
    if (blockIdx.x < GEMB) {
        bool f32 = sniff_f32((const unsigned int*)xv);
        mgemm1_body(blockIdx.x, xv, Wt1, as1, ad1, h1b, asrc1, adst1, f32);
        return;
    }
    int bb = blockIdx.x - GEMB;               // fill range: SAME 4-edge geometry as prep's degree range
    bool i64 = sniff_i64(ei);
    int i0 = (bb * 256 + threadIdx.x) * 4;
    if (i0 >= ET) return;
    int g = bb & 7;                           // same blockIdx->g map as prep
    int s[4], d[4];
    edge_s4(ei, i0, i64, s);
    edge_d4(ei, i0, i64, d);
    if (i0 + 3 < ET) {
        int4 rv = *(const int4*)(rank + i0);
        int r[4] = {rv.x, rv.y, rv.z, rv.w};
        #pragma unroll
        for (int e = 0; e < 4; ++e)
            col[deg8off[(size_t)g * NN + d[e]] + r[e]] = s[e];
    } else {
        #pragma unroll
        for (int e = 0; e < 4; ++e)
            if (i0 + e < ET) col[deg8off[(size_t)g * NN + d[e]] + rank[i0 + e]] = s[e];
    }
}

// ---------------- layer-1 aggregation (round-2 proven form) + FUSED layer-2 GEMM epilogue ----------------
// Main loop: one wave per dst node, lane covers dims 2l,2l+1, scalar 4B gathers (43.3us measured, 0 conflicts).
// Epilogue: hmid row staged fp32 in per-wave LDS; lane n computes h2[n] = hmid . Wt2[n] (L2-resident 16KB),
// then alpha2 dots via shfl reduce. Kills the separate mgemm2 kernel + the 12.8MB hmidb round-trip.
__global__ __launch_bounds__(256) void agg1_kernel(const unsigned int* __restrict__ xw,
                                                   const int* __restrict__ rowptr, const int* __restrict__ col,
                                                   const ushort_t* __restrict__ h1b,
                                                   const float* __restrict__ asrc, const float* __restrict__ adst,
                                                   const void* b1, const ushort_t* __restrict__ Wt2,
                                                   const void* as2, const void* ad2,
                                                   ushort_t* __restrict__ h2b,
                                                   float* __restrict__ asrc2, float* __restrict__ adst2) {
    __shared__ float wle[4][8 * 72];
    __shared__ int loff[4][64];
    __shared__ float hsm[4][128];
    bool f32 = sniff_f32(xw);
    int lane = threadIdx.x & 63, wid = threadIdx.x >> 6;
    int d = blockIdx.x * 4 + wid;
    if (d >= NN) return;                 // per-wave LDS only; no __syncthreads in this kernel
    int start = rowptr[d], end = rowptr[d + 1];
    int hB = lane >> 3;                  // head of dims 2*lane, 2*lane+1
    const float4* dp = (const float4*)(adst + (size_t)d * 8);
    float4 ad0 = dp[0], ad1 = dp[1];     // wave-uniform broadcast load
    const char* hb = (const char*)h1b + lane * 4;
    float acc0 = 0.f, acc1 = 0.f, ssum = 0.f;
    for (int chunk = start; chunk < end; chunk += 64) {
        int cnt = min(64, end - chunk);
        int c = (chunk + lane < end) ? col[chunk + lane] : 0;
        loff[wid][lane] = c << 8;        // byte offset of 256B h1b row
        if (lane < cnt) {
            const float4* ap = (const float4*)(asrc + (size_t)c * 8);
            float4 s0 = ap[0], s1 = ap[1];
            wle[wid][0 * 72 + lane] = __expf(lrelu(s0.x + ad0.x));
            wle[wid][1 * 72 + lane] = __expf(lrelu(s0.y + ad0.y));
            wle[wid][2 * 72 + lane] = __expf(lrelu(s0.z + ad0.z));
            wle[wid][3 * 72 + lane] = __expf(lrelu(s0.w + ad0.w));
            wle[wid][4 * 72 + lane] = __expf(lrelu(s1.x + ad1.x));
            wle[wid][5 * 72 + lane] = __expf(lrelu(s1.y + ad1.y));
            wle[wid][6 * 72 + lane] = __expf(lrelu(s1.z + ad1.z));
            wle[wid][7 * 72 + lane] = __expf(lrelu(s1.w + ad1.w));
        }
        #pragma unroll 8
        for (int j = 0; j < cnt; ++j) {
            int off = loff[wid][j];
            float ex = wle[wid][hB * 72 + j];
            unsigned int hv = *(const unsigned int*)(hb + off);
            ssum += ex;
            acc0 = fmaf(ex, __uint_as_float(hv << 16), acc0);
            acc1 = fmaf(ex, __uint_as_float(hv & 0xffff0000u), acc1);
        }
    }
    float inv = 1.f / (ssum + 1e-16f);
    float o0 = fmaf(acc0, inv, ldf(b1, lane * 2, f32));
    float o1 = fmaf(acc1, inv, ldf(b1, lane * 2 + 1, f32));
    o0 = (o0 > 0.f) ? o0 : (__expf(o0) - 1.f);   // ELU
    o1 = (o1 > 0.f) ? o1 : (__expf(o1) - 1.f);
    hsm[wid][lane * 2] = o0;
    hsm[wid][lane * 2 + 1] = o1;
    // ---- fused layer-2 matvec: lane n computes h2[n] over fp32 hmid (more accurate than bf16 round-trip) ----
    const ushort_t* w2 = Wt2 + (size_t)lane * 128;
    float h2 = 0.f;
    #pragma unroll
    for (int kk = 0; kk < 16; ++kk) {
        bf16x8 wv = *(const bf16x8*)(w2 + kk * 8);
        const float* hp = &hsm[wid][kk * 8];   // broadcast reads, conflict-free
        h2 = fmaf(hp[0], bf2f((ushort_t)wv[0]), h2);
        h2 = fmaf(hp[1], bf2f((ushort_t)wv[1]), h2);
        h2 = fmaf(hp[2], bf2f((ushort_t)wv[2]), h2);
        h2 = fmaf(hp[3], bf2f((ushort_t)wv[3]), h2);
        h2 = fmaf(hp[4], bf2f((ushort_t)wv[4]), h2);
        h2 = fmaf(hp[5], bf2f((ushort_t)wv[5]), h2);
        h2 = fmaf(hp[6], bf2f((ushort_t)wv[6]), h2);
        h2 = fmaf(hp[7], bf2f((ushort_t)wv[7]), h2);
    }
    float as = ldf(as2, lane, f32);
    float ad = ldf(ad2, lane, f32);
    float ps = h2 * as, pd = h2 * ad;
    #pragma unroll
    for (int off = 1; off < 64; off <<= 1) {
        ps += __shfl_xor(ps, off);
        pd += __shfl_xor(pd, off);
    }
    h2b[(size_t)d * 64 + lane] = f2bf(h2);
    if (lane == 0) { asrc2[d] = ps; adst2[d] = pd; }
}

// ---------------- layer-2 aggregation: wide-gather (8 edges x 1KB per VMEM instr) + log_softmax ----------------
__global__ __launch_bounds__(256) void agg2_kernel(const unsigned int* __restrict__ xw,
                                                   const int* __restrict__ rowptr, const int* __restrict__ col,
                                                   const ushort_t* __restrict__ h2b,
                                                   const float* __restrict__ asrc, const float* __restrict__ adst,
                                                   const void* b2, float* __restrict__ out) {
    __shared__ float wle[4][64];
    __shared__ int loff[4][64];
    bool f32 = sniff_f32(xw);
    int lane = threadIdx.x & 63, wid = threadIdx.x >> 6;
    int d = blockIdx.x * 4 + wid;
    if (d >= NN) return;
    int start = rowptr[d], end = rowptr[d + 1];
    int sub = lane & 7;                  // dim group: classes [8*sub, 8*sub+8)
    int eg  = lane >> 3;                 // edge group 0..7
    float ad = adst[d];
    const char* hb = (const char*)h2b + sub * 16;
    float acc[8] = {0.f, 0.f, 0.f, 0.f, 0.f, 0.f, 0.f, 0.f};
    float ssum = 0.f;
    for (int chunk = start; chunk < end; chunk += 64) {
        int cnt = min(64, end - chunk);
        int c = (chunk + lane < end) ? col[chunk + lane] : 0;
        loff[wid][lane] = c << 7;        // byte offset of 128B h2b row (0 for tail: safe)
        float e = 0.f;
        if (lane < cnt) e = __expf(lrelu(asrc[c] + ad));
        wle[wid][lane] = e;
        int niter = (cnt + 7) >> 3;
        #pragma unroll 2
        for (int jj = 0; jj < niter; ++jj) {
            int j = jj * 8 + eg;
            int off = loff[wid][j];
            float ex = wle[wid][j];
            uint4 hv = *(const uint4*)(hb + off);
            ssum += ex;
            acc[0] = fmaf(ex, __uint_as_float(hv.x << 16), acc[0]);
            acc[1] = fmaf(ex, __uint_as_float(hv.x & 0xffff0000u), acc[1]);
            acc[2] = fmaf(ex, __uint_as_float(hv.y << 16), acc[2]);
            acc[3] = fmaf(ex, __uint_as_float(hv.y & 0xffff0000u), acc[3]);
            acc[4] = fmaf(ex, __uint_as_float(hv.z << 16), acc[4]);
            acc[5] = fmaf(ex, __uint_as_float(hv.z & 0xffff0000u), acc[5]);
            acc[6] = fmaf(ex, __uint_as_float(hv.w << 16), acc[6]);
            acc[7] = fmaf(ex, __uint_as_float(hv.w & 0xffff0000u), acc[7]);
        }
    }
    #pragma unroll
    for (int off = 8; off < 64; off <<= 1) {
        ssum += __shfl_xor(ssum, off);
        #pragma unroll
        for (int k = 0; k < 8; ++k) acc[k] += __shfl_xor(acc[k], off);
    }
    if (eg == 0) {                        // lanes 0..7 hold the full 64-class row, 8 classes each
        float inv = 1.f / (ssum + 1e-16f);
        float o[8];
        #pragma unroll
        for (int k = 0; k < 8; ++k) o[k] = fmaf(acc[k], inv, ldf(b2, sub * 8 + k, f32));
        float mm = o[0];
        #pragma unroll
        for (int k = 1; k < 8; ++k) mm = fmaxf(mm, o[k]);
        #pragma unroll
        for (int off = 1; off < 8; off <<= 1) mm = fmaxf(mm, __shfl_xor(mm, off));
        float ts = 0.f;
        #pragma unroll
        for (int k = 0; k < 8; ++k) ts += __expf(o[k] - mm);
        #pragma unroll
        for (int off = 1; off < 8; off <<= 1) ts += __shfl_xor(ts, off);
        float lg = mm + __logf(ts);
        float4 w0, w1, l0, l1;
        w0.x = o[0]; w0.y = o[1]; w0.z = o[2]; w0.w = o[3];
        w1.x = o[4]; w1.y = o[5]; w1.z = o[6]; w1.w = o[7];
        l0.x = o[0] - lg; l0.y = o[1] - lg; l0.z = o[2] - lg; l0.w = o[3] - lg;
        l1.x = o[4] - lg; l1.y = o[5] - lg; l1.z = o[6] - lg; l1.w = o[7] - lg;
        float* op = out + (size_t)d * 64 + sub * 8;
        *(float4*)op = w0;
        *(float4*)(op + 4) = w1;
        float* lp = out + (size_t)NN * 64 + (size_t)d * 64 + sub * 8;
        *(float4*)lp = l0;
        *(float4*)(lp + 4) = l1;
    }
}

extern "C" void kernel_launch(void* const* d_in, const int* in_sizes, int n_in,
                              void* d_out, int out_size, void* d_ws, size_t ws_size,
                              hipStream_t stream) {
    const void* x   = d_in[0];
    const int*  ei  = (const int*)d_in[1];
    const void* W1  = d_in[2];
    const void* as1 = d_in[3];
    const void* ad1 = d_in[4];
    const void* b1  = d_in[5];
    const void* W2  = d_in[6];
    const void* as2 = d_in[7];
    const void* ad2 = d_in[8];
    const void* b2  = d_in[9];
    float* out = (float*)d_out;

    char* w = (char*)d_ws;
    auto alloc = [&](size_t bytes) {
        void* p = (void*)w;
        w += (bytes + 255) & ~(size_t)255;
        return p;
    };
    int* deg8     = (int*)alloc((size_t)8 * NN * 4 + 4096);   // +state tail (zeroed together)
    unsigned long long* state = (unsigned long long*)((char*)deg8 + (size_t)8 * NN * 4);
    int* rowptr   = (int*)alloc((size_t)(NN + 1) * 4);
    int* rank     = (int*)alloc((size_t)ET * 4);
    int* colx     = (int*)alloc((size_t)ET * 4);
    ushort_t* Wt1 = (ushort_t*)alloc((size_t)128 * 128 * 2);
    ushort_t* Wt2 = (ushort_t*)alloc((size_t)64 * 128 * 2);
    ushort_t* h1b = (ushort_t*)alloc((size_t)NN * 128 * 2);
    float* asrc1  = (float*)alloc((size_t)NN * 8 * 4);
    float* adst1  = (float*)alloc((size_t)NN * 8 * 4);
    ushort_t* h2b = (ushort_t*)alloc((size_t)NN * 64 * 2);
    float* asrc2  = (float*)alloc((size_t)NN * 4);
    float* adst2  = (float*)alloc((size_t)NN * 4);

    hipMemsetAsync(deg8, 0, (size_t)8 * NN * 4 + (size_t)NCH * 8, stream);

    prep_kernel<<<DEG4B + WPB, 256, 0, stream>>>(ei, deg8, rank, (const unsigned int*)x, W1, W2, Wt1, Wt2);
    scan_kernel<<<NCH, 256, 0, stream>>>(deg8, rowptr, state);
    gemm1_fill_kernel<<<GEMB + DEG4B, 256, 0, stream>>>(x, Wt1, as1, ad1, h1b, asrc1, adst1,
                                                        ei, deg8, rank, colx);
    agg1_kernel<<<NODB, 256, 0, stream>>>((const unsigned int*)x, rowptr, colx, h1b,
                                          asrc1, adst1, b1, Wt2, as2, ad2, h2b, asrc2, adst2);
    agg2_kernel<<<NODB, 256, 0, stream>>>((const unsigned int*)x, rowptr, colx, h2b,
                                          asrc2, adst2, b2, out);
}

// Round 6
// 247.106 us; speedup vs baseline: 1.6381x; 1.5130x over previous
//
#include <hip/hip_runtime.h>

#define NN 50000
#define EE 800000
#define ET (EE + NN)
#define NCH ((NN + 255) / 256)                       // 196 scan chunks
#define DEG4B ((ET + 1023) / 1024)                   // 831 degree/fill blocks (4 edges/thread)
#define WPB ((128 * 128 + 128 * 64 + 255) / 256)     // 96 wtprep blocks
#define GEMB ((NN + 63) / 64)                        // 782 gemm blocks
#define NODB ((NN + 3) / 4)                          // 12500 per-node-wave blocks

typedef unsigned short ushort_t;
using bf16x8 = __attribute__((ext_vector_type(8))) short;
using f32x4  = __attribute__((ext_vector_type(4))) float;

__device__ __forceinline__ float bf2f(ushort_t u) {
    return __uint_as_float(((unsigned int)u) << 16);
}
__device__ __forceinline__ ushort_t f2bf(float f) {
    unsigned int u = __float_as_uint(f);
    u += 0x7fffu + ((u >> 16) & 1u);
    return (ushort_t)(u >> 16);
}
__device__ __forceinline__ float lrelu(float e) {
    return fmaxf(e, 0.f) + 0.2f * fminf(e, 0.f);
}
__device__ __forceinline__ float ldf(const void* p, int i, bool f32) {
    return f32 ? ((const float*)p)[i] : bf2f(((const ushort_t*)p)[i]);
}

// ---- block-local dtype sniffers (per-wave ballot) ----
__device__ __forceinline__ bool sniff_f32(const unsigned int* __restrict__ xw) {
    int lane = threadIdx.x & 63;
    float v = __uint_as_float(xw[lane]);
    float a = fabsf(v);
    bool ok = (a > 1e-6f && a < 1e6f) || v == 0.f;
    unsigned long long m = __ballot(ok);
    return __popcll(m) >= 48;
}
__device__ __forceinline__ bool sniff_i64(const int* __restrict__ eiw) {
    int lane = threadIdx.x & 63;
    unsigned long long m = __ballot(eiw[2 * lane + 1] != 0);
    return __popcll(m) <= 4;
}

// 4-edge batched src/dst fetch. Thread's 4 edges never straddle the EE boundary
// (EE % 4 == 0 and i0 % 4 == 0), so the vector paths are safe.
__device__ __forceinline__ void edge_d4(const int* __restrict__ ei, int i0, bool i64, int (&d)[4]) {
    if (i0 < EE) {
        if (i64) {
            int4 r = *(const int4*)(ei + 2 * (size_t)(EE + i0));
            int4 u = *(const int4*)(ei + 2 * (size_t)(EE + i0) + 4);
            d[0] = r.x; d[1] = r.z; d[2] = u.x; d[3] = u.z;
        } else {
            int4 dv = *(const int4*)(ei + (size_t)EE + i0);
            d[0] = dv.x; d[1] = dv.y; d[2] = dv.z; d[3] = dv.w;
        }
    } else {
        #pragma unroll
        for (int e = 0; e < 4; ++e) d[e] = i0 + e - EE;   // self-loops (guard on use)
    }
}
__device__ __forceinline__ void edge_s4(const int* __restrict__ ei, int i0, bool i64, int (&s)[4]) {
    if (i0 < EE) {
        if (i64) {
            int4 p = *(const int4*)(ei + 2 * (size_t)i0);
            int4 q = *(const int4*)(ei + 2 * (size_t)i0 + 4);
            s[0] = p.x; s[1] = p.z; s[2] = q.x; s[3] = q.z;
        } else {
            int4 sv = *(const int4*)(ei + (size_t)i0);
            s[0] = sv.x; s[1] = sv.y; s[2] = sv.z; s[3] = sv.w;
        }
    } else {
        #pragma unroll
        for (int e = 0; e < 4; ++e) s[e] = i0 + e - EE;
    }
}

// ---------------- L1: degree+rank (4 edges/thread -> 4 atomics in flight) + W pre-transpose ----------------
__global__ __launch_bounds__(256) void prep_kernel(const int* __restrict__ ei, int* __restrict__ deg8,
                                                   int* __restrict__ rank,
                                                   const unsigned int* __restrict__ xw,
                                                   const void* W1v, const void* W2v,
                                                   ushort_t* __restrict__ Wt1, ushort_t* __restrict__ Wt2) {
    int b = blockIdx.x;
    if (b < DEG4B) {
        bool i64 = sniff_i64(ei);
        int i0 = (b * 256 + threadIdx.x) * 4;
        if (i0 >= ET) return;
        int g = b & 7;                        // blockIdx->XCD round-robin: atomic lines stay in one L2
        int d[4], r[4];
        edge_d4(ei, i0, i64, d);
        #pragma unroll
        for (int e = 0; e < 4; ++e)
            if (i0 + e < ET) r[e] = atomicAdd(&deg8[(size_t)g * NN + d[e]], 1);
        if (i0 + 3 < ET) {
            int4 rv; rv.x = r[0]; rv.y = r[1]; rv.z = r[2]; rv.w = r[3];
            *(int4*)(rank + i0) = rv;
        } else {
            #pragma unroll
            for (int e = 0; e < 4; ++e) if (i0 + e < ET) rank[i0 + e] = r[e];
        }
    } else {
        bool f32 = sniff_f32(xw);
        int i = (b - DEG4B) * 256 + threadIdx.x;
        if (i < 128 * 128) {                  // W1[k][nc] -> Wt1[nc][k]
            int k = i >> 7, nc = i & 127;
            ushort_t v = f32 ? f2bf(((const float*)W1v)[i]) : ((const ushort_t*)W1v)[i];
            Wt1[nc * 128 + k] = v;
        }
        int j = i - 128 * 128;
        if (j >= 0 && j < 128 * 64) {         // W2[k][nc] -> Wt2[nc][k]
            int k = j >> 6, nc = j & 63;
            ushort_t v = f32 ? f2bf(((const float*)W2v)[j]) : ((const ushort_t*)W2v)[j];
            Wt2[nc * 128 + k] = v;
        }
    }
}

// ---------------- scan: all-publish-then-all-read (no serial lookback chain) ----------------
#define FLG_A (1ull << 62)

__global__ __launch_bounds__(256) void scan_kernel(int* __restrict__ deg8, int* __restrict__ rowptr,
                                                   unsigned long long* __restrict__ state) {
    __shared__ int wsum[4];
    __shared__ int bpref;
    int b = blockIdx.x;
    int t = threadIdx.x;
    int node = b * 256 + t;
    int lane = t & 63, wid = t >> 6;
    int dv[8];
    int v = 0;
    if (node < NN) {
        #pragma unroll
        for (int g = 0; g < 8; ++g) {
            dv[g] = deg8[(size_t)g * NN + node];
            v += dv[g];
        }
    }
    int x = v;
    #pragma unroll
    for (int off = 1; off < 64; off <<= 1) {
        int y = __shfl_up(x, off);
        if (lane >= off) x += y;
    }
    if (lane == 63) wsum[wid] = x;
    __syncthreads();
    if (t < 4) {
        int s = wsum[t];
        #pragma unroll
        for (int off = 1; off < 4; off <<= 1) {
            int y = __shfl_up(s, off);
            if (t >= off) s += y;
        }
        wsum[t] = s;
    }
    __syncthreads();
    int total = wsum[3];                      // block aggregate
    if (t == 0) atomicExch(&state[b], FLG_A | (unsigned long long)(unsigned)total);
    if (t < 64) {                             // wave-parallel prefix: read all predecessors
        int p = 0;
        #pragma unroll
        for (int w = 0; w < (NCH + 63) / 64; ++w) {
            int j = w * 64 + t;
            unsigned long long sv = 0;
            if (j < b) {
                do { sv = atomicAdd(&state[j], 0ull); __builtin_amdgcn_s_sleep(1); } while (!(sv >> 62));
            }
            p += (int)(unsigned)(sv & 0xffffffffull);
        }
        #pragma unroll
        for (int off = 1; off < 64; off <<= 1) p += __shfl_xor(p, off);
        if (t == 0) bpref = p;
    }
    __syncthreads();
    int excl = x - v + ((wid > 0) ? wsum[wid - 1] : 0);
    if (node < NN) {
        int run = bpref + excl;
        rowptr[node] = run;
        #pragma unroll
        for (int g = 0; g < 8; ++g) {         // deg8 becomes per-slice exclusive offsets for fill
            deg8[(size_t)g * NN + node] = run;
            run += dv[g];
        }
    }
    if (b == NCH - 1 && t == 0) rowptr[NN] = bpref + total;
}

// ---------------- layer-1 MFMA GEMM body (A streamed global->VGPR, B (Wt1) L2-resident) ----------------
__device__ __forceinline__ void mgemm1_body(int bid, const void* Av, const ushort_t* __restrict__ Wt,
                                            const void* a_src, const void* a_dst,
                                            ushort_t* __restrict__ outb, float* __restrict__ asrc,
                                            float* __restrict__ adst, bool f32) {
    constexpr int K = 128;
    constexpr int NCT = 8;
    int t = threadIdx.x;
    int lane = t & 63, wid = t >> 6;
    int m = lane & 15, quad = lane >> 4;
    int rbase = bid * 64 + wid * 16;
    int row = rbase + m;
    bool rok = row < NN;

    bf16x8 af[4];
    if (rok) {
        if (!f32) {
            const ushort_t* ap = (const ushort_t*)Av + (size_t)row * K + quad * 8;
            #pragma unroll
            for (int kk = 0; kk < 4; ++kk) af[kk] = *(const bf16x8*)(ap + kk * 32);
        } else {
            const float* ap = (const float*)Av + (size_t)row * K + quad * 8;
            #pragma unroll
            for (int kk = 0; kk < 4; ++kk) {
                float4 q0 = *(const float4*)(ap + kk * 32);
                float4 q1 = *(const float4*)(ap + kk * 32 + 4);
                bf16x8 v;
                v[0] = (short)f2bf(q0.x); v[1] = (short)f2bf(q0.y);
                v[2] = (short)f2bf(q0.z); v[3] = (short)f2bf(q0.w);
                v[4] = (short)f2bf(q1.x); v[5] = (short)f2bf(q1.y);
                v[6] = (short)f2bf(q1.z); v[7] = (short)f2bf(q1.w);
                af[kk] = v;
            }
        }
    } else {
        #pragma unroll
        for (int kk = 0; kk < 4; ++kk) af[kk] = (bf16x8){0, 0, 0, 0, 0, 0, 0, 0};
    }

    f32x4 acc[NCT];
    #pragma unroll
    for (int c = 0; c < NCT; ++c) acc[c] = (f32x4){0.f, 0.f, 0.f, 0.f};

    const ushort_t* wp = Wt + (size_t)m * K + quad * 8;
    #pragma unroll
    for (int c = 0; c < NCT; ++c) {
        const ushort_t* wc = wp + (size_t)c * 16 * K;
        #pragma unroll
        for (int kk = 0; kk < 4; ++kk) {
            bf16x8 bf = *(const bf16x8*)(wc + kk * 32);
            acc[c] = __builtin_amdgcn_mfma_f32_16x16x32_bf16(af[kk], bf, acc[c], 0, 0, 0);
        }
    }

    int orow0 = rbase + quad * 4;
    #pragma unroll
    for (int c = 0; c < NCT; ++c) {
        #pragma unroll
        for (int r = 0; r < 4; ++r) {
            int orow = orow0 + r;
            if (orow < NN) outb[(size_t)orow * 128 + c * 16 + m] = f2bf(acc[c][r]);
        }
    }

    #pragma unroll
    for (int c = 0; c < NCT; ++c) {           // c == head
        float as = ldf(a_src, c * 16 + m, f32);
        float ad = ldf(a_dst, c * 16 + m, f32);
        float ps[4], pd[4];
        #pragma unroll
        for (int r = 0; r < 4; ++r) { ps[r] = acc[c][r] * as; pd[r] = acc[c][r] * ad; }
        #pragma unroll
        for (int stp = 1; stp < 16; stp <<= 1) {
            #pragma unroll
            for (int r = 0; r < 4; ++r) {
                ps[r] += __shfl_xor(ps[r], stp);
                pd[r] += __shfl_xor(pd[r], stp);
            }
        }
        if (m == 0) {
            #pragma unroll
            for (int r = 0; r < 4; ++r) {
                int orow = orow0 + r;
                if (orow < NN) {
                    asrc[(size_t)orow * 8 + c] = ps[r];
                    adst[(size_t)orow * 8 + c] = pd[r];
                }
            }
        }
    }
}

// ---------------- layer-2 MFMA GEMM: hmid (bf16) @ Wt2 -> h2b + alpha2 scalars ----------------
__global__ __launch_bounds__(256) void mgemm2_kernel(const ushort_t* __restrict__ Av, const ushort_t* __restrict__ Wt,
                                                     const void* a_src, const void* a_dst,
                                                     ushort_t* __restrict__ outb, float* __restrict__ asrc,
                                                     float* __restrict__ adst, const unsigned int* __restrict__ xw) {
    constexpr int K = 128;
    constexpr int NCT = 4;
    bool f32 = sniff_f32(xw);
    int t = threadIdx.x;
    int lane = t & 63, wid = t >> 6;
    int m = lane & 15, quad = lane >> 4;
    int rbase = blockIdx.x * 64 + wid * 16;
    int row = rbase + m;
    bool rok = row < NN;

    bf16x8 af[4];
    if (rok) {
        const ushort_t* ap = Av + (size_t)row * K + quad * 8;
        #pragma unroll
        for (int kk = 0; kk < 4; ++kk) af[kk] = *(const bf16x8*)(ap + kk * 32);
    } else {
        #pragma unroll
        for (int kk = 0; kk < 4; ++kk) af[kk] = (bf16x8){0, 0, 0, 0, 0, 0, 0, 0};
    }

    f32x4 acc[NCT];
    #pragma unroll
    for (int c = 0; c < NCT; ++c) acc[c] = (f32x4){0.f, 0.f, 0.f, 0.f};

    const ushort_t* wp = Wt + (size_t)m * K + quad * 8;
    #pragma unroll
    for (int c = 0; c < NCT; ++c) {
        const ushort_t* wc = wp + (size_t)c * 16 * K;
        #pragma unroll
        for (int kk = 0; kk < 4; ++kk) {
            bf16x8 bf = *(const bf16x8*)(wc + kk * 32);
            acc[c] = __builtin_amdgcn_mfma_f32_16x16x32_bf16(af[kk], bf, acc[c], 0, 0, 0);
        }
    }

    int orow0 = rbase + quad * 4;
    #pragma unroll
    for (int c = 0; c < NCT; ++c) {
        #pragma unroll
        for (int r = 0; r < 4; ++r) {
            int orow = orow0 + r;
            if (orow < NN) outb[(size_t)orow * 64 + c * 16 + m] = f2bf(acc[c][r]);
        }
    }

    float ps[4] = {0.f, 0.f, 0.f, 0.f}, pd[4] = {0.f, 0.f, 0.f, 0.f};
    #pragma unroll
    for (int c = 0; c < NCT; ++c) {
        float as = ldf(a_src, c * 16 + m, f32);
        float ad = ldf(a_dst, c * 16 + m, f32);
        #pragma unroll
        for (int r = 0; r < 4; ++r) {
            ps[r] = fmaf(acc[c][r], as, ps[r]);
            pd[r] = fmaf(acc[c][r], ad, pd[r]);
        }
    }
    #pragma unroll
    for (int stp = 1; stp < 16; stp <<= 1) {
        #pragma unroll
        for (int r = 0; r < 4; ++r) {
            ps[r] += __shfl_xor(ps[r], stp);
            pd[r] += __shfl_xor(pd[r], stp);
        }
    }
    if (m == 0) {
        #pragma unroll
        for (int r = 0; r < 4; ++r) {
            int orow = orow0 + r;
            if (orow < NN) { asrc[orow] = ps[r]; adst[orow] = pd[r]; }
        }
    }
}

// ---------------- L3: layer-1 GEMM + CSR fill (4 edges/thread), fused by block range ----------------
__global__ __launch_bounds__(256) void gemm1_fill_kernel(const void* xv, const ushort_t* __restrict__ Wt1,
                                                         const void* as1, const void* ad1,
                                                         ushort_t* __restrict__ h1b,
                                                         float* __restrict__ asrc1, float* __restrict__ adst1,
                                                         const int* __restrict__ ei,
                                                         const int* __restrict__ deg8off,
                                                         const int* __restrict__ rank, int* __restrict__ col) {
    if (blockIdx.x < GEMB) {
        bool f32 = sniff_f32((const unsigned int*)xv);
        mgemm1_body(blockIdx.x, xv, Wt1, as1, ad1, h1b, asrc1, adst1, f32);
        return;
    }
    int bb = blockIdx.x - GEMB;               // fill range: SAME 4-edge geometry as prep's degree range
    bool i64 = sniff_i64(ei);
    int i0 = (bb * 256 + threadIdx.x) * 4;
    if (i0 >= ET) return;
    int g = bb & 7;                           // same blockIdx->g map as prep
    int s[4], d[4];
    edge_s4(ei, i0, i64, s);
    edge_d4(ei, i0, i64, d);
    if (i0 + 3 < ET) {
        int4 rv = *(const int4*)(rank + i0);
        int r[4] = {rv.x, rv.y, rv.z, rv.w};
        #pragma unroll
        for (int e = 0; e < 4; ++e)
            col[deg8off[(size_t)g * NN + d[e]] + r[e]] = s[e];
    } else {
        #pragma unroll
        for (int e = 0; e < 4; ++e)
            if (i0 + e < ET) col[deg8off[(size_t)g * NN + d[e]] + rank[i0 + e]] = s[e];
    }
}

// ---------------- layer-1 aggregation: round-2 proven form (43.3us, VGPR 32, occ ~63%) ----------------
__global__ __launch_bounds__(256) void agg1_kernel(const unsigned int* __restrict__ xw,
                                                   const int* __restrict__ rowptr, const int* __restrict__ col,
                                                   const ushort_t* __restrict__ h1b,
                                                   const float* __restrict__ asrc, const float* __restrict__ adst,
                                                   const void* b1, ushort_t* __restrict__ hmidb) {
    __shared__ float wle[4][8 * 72];
    __shared__ int loff[4][64];
    bool f32 = sniff_f32(xw);
    int lane = threadIdx.x & 63, wid = threadIdx.x >> 6;
    int d = blockIdx.x * 4 + wid;
    if (d >= NN) return;                 // per-wave LDS only; no __syncthreads in this kernel
    int start = rowptr[d], end = rowptr[d + 1];
    int hB = lane >> 3;                  // head of dims 2*lane, 2*lane+1
    const float4* dp = (const float4*)(adst + (size_t)d * 8);
    float4 ad0 = dp[0], ad1 = dp[1];     // wave-uniform broadcast load
    const char* hb = (const char*)h1b + lane * 4;
    float acc0 = 0.f, acc1 = 0.f, ssum = 0.f;
    for (int chunk = start; chunk < end; chunk += 64) {
        int cnt = min(64, end - chunk);
        int c = (chunk + lane < end) ? col[chunk + lane] : 0;
        loff[wid][lane] = c << 8;        // byte offset of 256B h1b row
        if (lane < cnt) {
            const float4* ap = (const float4*)(asrc + (size_t)c * 8);
            float4 s0 = ap[0], s1 = ap[1];
            wle[wid][0 * 72 + lane] = __expf(lrelu(s0.x + ad0.x));
            wle[wid][1 * 72 + lane] = __expf(lrelu(s0.y + ad0.y));
            wle[wid][2 * 72 + lane] = __expf(lrelu(s0.z + ad0.z));
            wle[wid][3 * 72 + lane] = __expf(lrelu(s0.w + ad0.w));
            wle[wid][4 * 72 + lane] = __expf(lrelu(s1.x + ad1.x));
            wle[wid][5 * 72 + lane] = __expf(lrelu(s1.y + ad1.y));
            wle[wid][6 * 72 + lane] = __expf(lrelu(s1.z + ad1.z));
            wle[wid][7 * 72 + lane] = __expf(lrelu(s1.w + ad1.w));
        }
        #pragma unroll 8
        for (int j = 0; j < cnt; ++j) {
            int off = loff[wid][j];
            float ex = wle[wid][hB * 72 + j];
            unsigned int hv = *(const unsigned int*)(hb + off);
            ssum += ex;
            acc0 = fmaf(ex, __uint_as_float(hv << 16), acc0);
            acc1 = fmaf(ex, __uint_as_float(hv & 0xffff0000u), acc1);
        }
    }
    float inv = 1.f / (ssum + 1e-16f);
    float o0 = fmaf(acc0, inv, ldf(b1, lane * 2, f32));
    float o1 = fmaf(acc1, inv, ldf(b1, lane * 2 + 1, f32));
    o0 = (o0 > 0.f) ? o0 : (__expf(o0) - 1.f);   // ELU
    o1 = (o1 > 0.f) ? o1 : (__expf(o1) - 1.f);
    unsigned int pk = ((unsigned int)f2bf(o1) << 16) | (unsigned int)f2bf(o0);
    *(unsigned int*)(hmidb + (size_t)d * 128 + lane * 2) = pk;
}

// ---------------- layer-2 aggregation: wide-gather (8 edges x 1KB per VMEM instr) + log_softmax ----------------
__global__ __launch_bounds__(256) void agg2_kernel(const unsigned int* __restrict__ xw,
                                                   const int* __restrict__ rowptr, const int* __restrict__ col,
                                                   const ushort_t* __restrict__ h2b,
                                                   const float* __restrict__ asrc, const float* __restrict__ adst,
                                                   const void* b2, float* __restrict__ out) {
    __shared__ float wle[4][64];
    __shared__ int loff[4][64];
    bool f32 = sniff_f32(xw);
    int lane = threadIdx.x & 63, wid = threadIdx.x >> 6;
    int d = blockIdx.x * 4 + wid;
    if (d >= NN) return;
    int start = rowptr[d], end = rowptr[d + 1];
    int sub = lane & 7;                  // dim group: classes [8*sub, 8*sub+8)
    int eg  = lane >> 3;                 // edge group 0..7
    float ad = adst[d];
    const char* hb = (const char*)h2b + sub * 16;
    float acc[8] = {0.f, 0.f, 0.f, 0.f, 0.f, 0.f, 0.f, 0.f};
    float ssum = 0.f;
    for (int chunk = start; chunk < end; chunk += 64) {
        int cnt = min(64, end - chunk);
        int c = (chunk + lane < end) ? col[chunk + lane] : 0;
        loff[wid][lane] = c << 7;        // byte offset of 128B h2b row (0 for tail: safe)
        float e = 0.f;
        if (lane < cnt) e = __expf(lrelu(asrc[c] + ad));
        wle[wid][lane] = e;
        int niter = (cnt + 7) >> 3;
        #pragma unroll 2
        for (int jj = 0; jj < niter; ++jj) {
            int j = jj * 8 + eg;
            int off = loff[wid][j];
            float ex = wle[wid][j];
            uint4 hv = *(const uint4*)(hb + off);
            ssum += ex;
            acc[0] = fmaf(ex, __uint_as_float(hv.x << 16), acc[0]);
            acc[1] = fmaf(ex, __uint_as_float(hv.x & 0xffff0000u), acc[1]);
            acc[2] = fmaf(ex, __uint_as_float(hv.y << 16), acc[2]);
            acc[3] = fmaf(ex, __uint_as_float(hv.y & 0xffff0000u), acc[3]);
            acc[4] = fmaf(ex, __uint_as_float(hv.z << 16), acc[4]);
            acc[5] = fmaf(ex, __uint_as_float(hv.z & 0xffff0000u), acc[5]);
            acc[6] = fmaf(ex, __uint_as_float(hv.w << 16), acc[6]);
            acc[7] = fmaf(ex, __uint_as_float(hv.w & 0xffff0000u), acc[7]);
        }
    }
    #pragma unroll
    for (int off = 8; off < 64; off <<= 1) {
        ssum += __shfl_xor(ssum, off);
        #pragma unroll
        for (int k = 0; k < 8; ++k) acc[k] += __shfl_xor(acc[k], off);
    }
    if (eg == 0) {                        // lanes 0..7 hold the full 64-class row, 8 classes each
        float inv = 1.f / (ssum + 1e-16f);
        float o[8];
        #pragma unroll
        for (int k = 0; k < 8; ++k) o[k] = fmaf(acc[k], inv, ldf(b2, sub * 8 + k, f32));
        float mm = o[0];
        #pragma unroll
        for (int k = 1; k < 8; ++k) mm = fmaxf(mm, o[k]);
        #pragma unroll
        for (int off = 1; off < 8; off <<= 1) mm = fmaxf(mm, __shfl_xor(mm, off));
        float ts = 0.f;
        #pragma unroll
        for (int k = 0; k < 8; ++k) ts += __expf(o[k] - mm);
        #pragma unroll
        for (int off = 1; off < 8; off <<= 1) ts += __shfl_xor(ts, off);
        float lg = mm + __logf(ts);
        float4 w0, w1, l0, l1;
        w0.x = o[0]; w0.y = o[1]; w0.z = o[2]; w0.w = o[3];
        w1.x = o[4]; w1.y = o[5]; w1.z = o[6]; w1.w = o[7];
        l0.x = o[0] - lg; l0.y = o[1] - lg; l0.z = o[2] - lg; l0.w = o[3] - lg;
        l1.x = o[4] - lg; l1.y = o[5] - lg; l1.z = o[6] - lg; l1.w = o[7] - lg;
        float* op = out + (size_t)d * 64 + sub * 8;
        *(float4*)op = w0;
        *(float4*)(op + 4) = w1;
        float* lp = out + (size_t)NN * 64 + (size_t)d * 64 + sub * 8;
        *(float4*)lp = l0;
        *(float4*)(lp + 4) = l1;
    }
}

extern "C" void kernel_launch(void* const* d_in, const int* in_sizes, int n_in,
                              void* d_out, int out_size, void* d_ws, size_t ws_size,
                              hipStream_t stream) {
    const void* x   = d_in[0];
    const int*  ei  = (const int*)d_in[1];
    const void* W1  = d_in[2];
    const void* as1 = d_in[3];
    const void* ad1 = d_in[4];
    const void* b1  = d_in[5];
    const void* W2  = d_in[6];
    const void* as2 = d_in[7];
    const void* ad2 = d_in[8];
    const void* b2  = d_in[9];
    float* out = (float*)d_out;

    char* w = (char*)d_ws;
    auto alloc = [&](size_t bytes) {
        void* p = (void*)w;
        w += (bytes + 255) & ~(size_t)255;
        return p;
    };
    int* deg8     = (int*)alloc((size_t)8 * NN * 4 + 4096);   // +state tail (zeroed together)
    unsigned long long* state = (unsigned long long*)((char*)deg8 + (size_t)8 * NN * 4);
    int* rowptr   = (int*)alloc((size_t)(NN + 1) * 4);
    int* rank     = (int*)alloc((size_t)ET * 4);
    int* colx     = (int*)alloc((size_t)ET * 4);
    ushort_t* Wt1 = (ushort_t*)alloc((size_t)128 * 128 * 2);
    ushort_t* Wt2 = (ushort_t*)alloc((size_t)64 * 128 * 2);
    ushort_t* h1b = (ushort_t*)alloc((size_t)NN * 128 * 2);
    float* asrc1  = (float*)alloc((size_t)NN * 8 * 4);
    float* adst1  = (float*)alloc((size_t)NN * 8 * 4);
    ushort_t* hmidb = (ushort_t*)alloc((size_t)NN * 128 * 2);
    ushort_t* h2b = (ushort_t*)alloc((size_t)NN * 64 * 2);
    float* asrc2  = (float*)alloc((size_t)NN * 4);
    float* adst2  = (float*)alloc((size_t)NN * 4);

    hipMemsetAsync(deg8, 0, (size_t)8 * NN * 4 + (size_t)NCH * 8, stream);

    prep_kernel<<<DEG4B + WPB, 256, 0, stream>>>(ei, deg8, rank, (const unsigned int*)x, W1, W2, Wt1, Wt2);
    scan_kernel<<<NCH, 256, 0, stream>>>(deg8, rowptr, state);
    gemm1_fill_kernel<<<GEMB + DEG4B, 256, 0, stream>>>(x, Wt1, as1, ad1, h1b, asrc1, adst1,
                                                        ei, deg8, rank, colx);
    agg1_kernel<<<NODB, 256, 0, stream>>>((const unsigned int*)x, rowptr, colx, h1b,
                                          asrc1, adst1, b1, hmidb);
    mgemm2_kernel<<<GEMB, 256, 0, stream>>>(hmidb, Wt2, as2, ad2, h2b, asrc2, adst2,
                                            (const unsigned int*)x);
    agg2_kernel<<<NODB, 256, 0, stream>>>((const unsigned int*)x, rowptr, colx, h2b,
                                          asrc2, adst2, b2, out);
}